// Round 9
// baseline (205.588 us; speedup 1.0000x reference)
//
#include <hip/hip_runtime.h>
#include <math.h>

#define SS 4096
#define EE 1024
#define HH 16
#define DD 64
#define RMAX 128     // max supported segment length (actual ~64 +/- 8)
#define NCOL 128     // colsum blocks in D1
#define NPROJ 192    // 3 m * 32 etiles * 2 rowblocks
#define NBG 64       // bgA GEMV blocks in D2
#define RSPLIT 4     // attn blocks per head

// ---------------------------------------------------------------------------
// ws layout (float offsets):
//   part   [NCOL][EE]      0        (x column-sum partials)
//   qb     [RMAX][EE]      131072   (zero-padded to Lp rows)
//   kb     [RMAX][EE]      262144
//   vb     [RMAX][EE]      393216
//   bgA    [EE]            524288   (V_all = S*bv + Wv.sumx)
//   betap  [64][64]        525312   (per attn-block beta slot)
//   alphap [64]            529408   (per attn-block alpha slot)
// Every cell consumed is produced earlier in the same call (poison-safe).
// 3 dispatches; dispatch boundaries are the only grid-wide sync.
// ---------------------------------------------------------------------------

__device__ __forceinline__ void seg_scan(const int* __restrict__ seg,
                                         const int* __restrict__ posp,
                                         int* sh, int& s0, int& L) {
    if (threadIdx.x == 0) { sh[0] = SS; sh[1] = -1; }
    __syncthreads();
    int sid = seg[posp[0]];
    int lmin = SS, lmax = -1;
    for (int i = threadIdx.x; i < SS; i += 256)
        if (seg[i] == sid) { lmin = min(lmin, i); lmax = max(lmax, i); }
#pragma unroll
    for (int off = 32; off; off >>= 1) {
        lmin = min(lmin, __shfl_xor(lmin, off));
        lmax = max(lmax, __shfl_xor(lmax, off));
    }
    if ((threadIdx.x & 63) == 0) { atomicMin(&sh[0], lmin); atomicMax(&sh[1], lmax); }
    __syncthreads();
    s0 = sh[0];
    L  = sh[1] - sh[0] + 1;
    if (L > RMAX) L = RMAX;
    if (L < 1)    L = 1;
}

// -------- D1: colsum partials (128 blk) || QKV projection (192 blk) --------
__global__ __launch_bounds__(256) void d1_kernel(
    const float* __restrict__ x,
    const float* __restrict__ Wq, const float* __restrict__ bq,
    const float* __restrict__ Wk, const float* __restrict__ bk,
    const float* __restrict__ Wv, const float* __restrict__ bv,
    const int* __restrict__ seg, const int* __restrict__ posp,
    float* __restrict__ ws) {
    __shared__ float xs[128 * 65];   // [k][r]
    __shared__ float ws2[128 * 36];  // [k][e], 32 e per block
    __shared__ int   sh[2];
    float* part = ws;
    float* qb   = ws + (size_t)NCOL * EE;
    float* kb   = qb + (size_t)RMAX * EE;
    float* vb   = kb + (size_t)RMAX * EE;

    int bid = blockIdx.x, tid = threadIdx.x;
    int lane = tid & 63, wave = tid >> 6;

    if (bid < NCOL) {
        int r0 = bid * (SS / NCOL);
        const float4* x4 = (const float4*)x;
        float4 a = make_float4(0.f, 0.f, 0.f, 0.f);
#pragma unroll 8
        for (int r = 0; r < SS / NCOL; ++r) {
            float4 v = x4[(size_t)(r0 + r) * 256 + tid];
            a.x += v.x; a.y += v.y; a.z += v.z; a.w += v.w;
        }
        ((float4*)part)[(size_t)bid * 256 + tid] = a;
        return;
    }

    int pid  = bid - NCOL;           // 0..191
    int m    = pid % 3;
    int rest = pid / 3;              // 0..63
    int et   = rest & 31;            // 32-col tile
    int ry   = rest >> 5;            // row-block 0/1

    int s0, L;
    seg_scan(seg, posp, sh, s0, L);
    int Lp = (L + 63) & ~63;
    int r0 = ry * 64;
    if (r0 >= Lp) return;

    const float* W = (m == 0) ? Wq : ((m == 1) ? Wk : Wv);
    const float* b = (m == 0) ? bq : ((m == 1) ? bk : bv);
    float*       y = (m == 0) ? qb : ((m == 1) ? kb : vb);

    float acc[8] = {0.f, 0.f, 0.f, 0.f, 0.f, 0.f, 0.f, 0.f};
    for (int kr = 0; kr < 8; ++kr) {
        int k0 = kr * 128;
        __syncthreads();
        for (int idx = tid; idx < 2048; idx += 256) {   // xs: 64 r x 32 k4
            int k4 = idx & 31, r = idx >> 5;
            float4 v = make_float4(0.f, 0.f, 0.f, 0.f);
            if (r0 + r < L)
                v = *(const float4*)(x + (size_t)(s0 + r0 + r) * EE + k0 + k4 * 4);
            xs[(k4 * 4 + 0) * 65 + r] = v.x;
            xs[(k4 * 4 + 1) * 65 + r] = v.y;
            xs[(k4 * 4 + 2) * 65 + r] = v.z;
            xs[(k4 * 4 + 3) * 65 + r] = v.w;
        }
        for (int idx = tid; idx < 1024; idx += 256) {   // ws2: 32 e x 32 k4
            int k4 = idx & 31, e = idx >> 5;
            float4 v = *(const float4*)(W + (size_t)(et * 32 + e) * EE + k0 + k4 * 4);
            ws2[(k4 * 4 + 0) * 36 + e] = v.x;
            ws2[(k4 * 4 + 1) * 36 + e] = v.y;
            ws2[(k4 * 4 + 2) * 36 + e] = v.z;
            ws2[(k4 * 4 + 3) * 36 + e] = v.w;
        }
        __syncthreads();
#pragma unroll 4
        for (int k = 0; k < 128; ++k) {
            float xr = xs[k * 65 + lane];
            const float4* wp = (const float4*)&ws2[k * 36 + (wave << 3)];
            float4 w0 = wp[0], w1 = wp[1];
            acc[0] += w0.x * xr; acc[1] += w0.y * xr;
            acc[2] += w0.z * xr; acc[3] += w0.w * xr;
            acc[4] += w1.x * xr; acc[5] += w1.y * xr;
            acc[6] += w1.z * xr; acc[7] += w1.w * xr;
        }
    }
    int rg = r0 + lane;               // < Lp always
    float4 o0 = make_float4(0.f, 0.f, 0.f, 0.f), o1 = o0;
    if (rg < L) {
        int eb = et * 32 + (wave << 3);
        float4 b0 = *(const float4*)&b[eb], b1 = *(const float4*)&b[eb + 4];
        o0 = make_float4(acc[0] + b0.x, acc[1] + b0.y, acc[2] + b0.z, acc[3] + b0.w);
        o1 = make_float4(acc[4] + b1.x, acc[5] + b1.y, acc[6] + b1.z, acc[7] + b1.w);
    }
    float* dst = y + (size_t)rg * EE + et * 32 + (wave << 3);
    *(float4*)dst       = o0;
    *(float4*)(dst + 4) = o1;
}

// -------- D2: bgA GEMV (64 blk) || attention beta/alpha (64 blk) --------
__global__ __launch_bounds__(256) void d2_kernel(
    const float* __restrict__ Wv, const float* __restrict__ bv,
    const int* __restrict__ seg, const int* __restrict__ posp,
    float* __restrict__ ws) {
    __shared__ float kT[64 * 129];
    __shared__ float sc[4 * 128];
    __shared__ float sxl[EE];
    __shared__ float vsum[64];
    __shared__ float mwp[4][64];
    __shared__ float awp[4];
    __shared__ int   sh[2];
    const float* part = ws;
    const float* qb   = ws + (size_t)NCOL * EE;
    const float* kb   = qb + (size_t)RMAX * EE;
    const float* vb   = kb + (size_t)RMAX * EE;
    float* bgA    = (float*)(vb + (size_t)RMAX * EE);
    float* betap  = bgA + EE;
    float* alphap = betap + 64 * 64;

    int bid = blockIdx.x, tid = threadIdx.x;
    int lane = tid & 63, wave = tid >> 6;

    if (bid < NBG) {
        // reduce part -> sxl (full sumx, redundant per block, L2/L3-hot)
        const float4* p4 = (const float4*)part;
        float4 s = make_float4(0.f, 0.f, 0.f, 0.f);
#pragma unroll 8
        for (int c = 0; c < NCOL; ++c) {
            float4 v = p4[(size_t)c * 256 + tid];
            s.x += v.x; s.y += v.y; s.z += v.z; s.w += v.w;
        }
        ((float4*)sxl)[tid] = s;
        __syncthreads();
        // 16 e's per block, 16 threads per e
        int e = bid * 16 + (tid >> 4);
        int j = tid & 15;
        const float4* wr  = (const float4*)(Wv + (size_t)e * EE);
        const float4* sx4 = (const float4*)sxl;
        float p = 0.f;
#pragma unroll
        for (int jj = 0; jj < 16; ++jj) {
            float4 w = wr[jj * 16 + j], z = sx4[jj * 16 + j];
            p += w.x * z.x + w.y * z.y + w.z * z.z + w.w * z.w;
        }
        p += __shfl_xor(p, 8);
        p += __shfl_xor(p, 4);
        p += __shfl_xor(p, 2);
        p += __shfl_xor(p, 1);
        if (j == 0) bgA[e] = p + (float)SS * bv[e];
        return;
    }

    int aid = bid - NBG;              // 0..63
    int h   = aid / RSPLIT;
    int q4  = aid % RSPLIT;
    int hD  = h * DD;

    int s0, L;
    seg_scan(seg, posp, sh, s0, L);
    int Lp = (L + 63) & ~63;
    int nt = Lp >> 6;

    // vsum[d] = sum_t vb[t][hD+d]  (padded rows are zero)
    {
        int d = tid >> 2, q = tid & 3;
        float s = 0.f;
        for (int t = q; t < Lp; t += 4) s += vb[(size_t)t * EE + hD + d];
        s += __shfl_xor(s, 1);
        s += __shfl_xor(s, 2);
        if (q == 0) vsum[d] = s;
    }
    // kT[d][t] = kb[t][hD+d]
    for (int idx = tid; idx < 64 * Lp; idx += 256) {
        int d = idx & 63, t = idx >> 6;
        kT[d * 129 + t] = kb[(size_t)t * EE + hD + d];
    }
    __syncthreads();

    float bw = 0.f;   // per-lane (d) sum of acc/Z
    float aw = 0.f;   // wave-uniform sum of exp(-m)/Z
    int rpb = Lp / RSPLIT;
    int rlo = q4 * rpb;
    int rhi = rlo + rpb; if (rhi > L) rhi = L;
    float* scw = sc + wave * 128;
    for (int r = rlo + wave; r < rhi; r += 4) {
        float qreg = qb[(size_t)r * EE + hD + lane];
        float mmax = 0.f;   // zero background participates in row max
        for (int c = 0; c < nt; ++c) {
            float s = 0.f;
            const float* kp = kT + c * 64 + lane;
#pragma unroll
            for (int d = 0; d < 64; ++d) s += __shfl(qreg, d) * kp[d * 129];
            scw[c * 64 + lane] = s;
            mmax = fmaxf(mmax, (c * 64 + lane) < L ? s : -3.0e38f);
        }
#pragma unroll
        for (int off = 32; off; off >>= 1) mmax = fmaxf(mmax, __shfl_xor(mmax, off));
        float Zl = 0.f;
        for (int c = 0; c < nt; ++c) {
            float w = ((c * 64 + lane) < L) ? __expf(scw[c * 64 + lane] - mmax) : 0.f;
            Zl += w;
            scw[c * 64 + lane] = w;
        }
#pragma unroll
        for (int off = 32; off; off >>= 1) Zl += __shfl_xor(Zl, off);
        float em = __expf(-mmax);
        float Z  = Zl + (float)(SS - L) * em;
        float acc = 0.f;
        for (int c = 0; c < nt; ++c) {
            const float* vp  = vb + (size_t)(c * 64) * EE + hD + lane;
            const float* scc = scw + c * 64;
#pragma unroll 16
            for (int tt = 0; tt < 64; ++tt) acc += scc[tt] * vp[(size_t)tt * EE];
        }
        float invZ = 1.0f / Z;
        bw += acc * invZ;
        aw += em * invZ;
    }
    mwp[wave][lane] = bw;
    if (lane == 0) awp[wave] = aw;
    __syncthreads();
    if (tid < 64) {
        float asum = awp[0] + awp[1] + awp[2] + awp[3];
        float beta = mwp[0][tid] + mwp[1][tid] + mwp[2][tid] + mwp[3][tid]
                   - asum * vsum[tid];
        betap[aid * 64 + tid] = beta;
        if (tid == 0) alphap[aid] = asum;
    }
}

// -------- D3: out[e] = bo[e] + Wo[e,:].(beta~ + alpha o bgA) / L --------
__global__ __launch_bounds__(256) void d3_kernel(
    const float* __restrict__ Wo, const float* __restrict__ bo,
    const int* __restrict__ seg, const int* __restrict__ posp,
    const float* __restrict__ ws, float* __restrict__ out) {
    __shared__ float z[EE];
    __shared__ int   sh[2];
    const float* bgA    = ws + (size_t)NCOL * EE + 3ull * RMAX * EE;
    const float* betap  = bgA + EE;
    const float* alphap = betap + 64 * 64;

    int tid = threadIdx.x;
    int lane = tid & 63, wave = tid >> 6;
    int s0, L;
    seg_scan(seg, posp, sh, s0, L);

    {   // z[j] = sum_q betap[(h*4+q)][d] + (sum_q alphap)*bgA[j]
        int h = tid >> 4;                 // float4 index tid -> head
        const float4* bp4 = (const float4*)betap;
        float4 bsum = make_float4(0.f, 0.f, 0.f, 0.f);
        float  asum = 0.f;
#pragma unroll
        for (int q = 0; q < RSPLIT; ++q) {
            float4 v = bp4[(h * RSPLIT + q) * 16 + (tid & 15)];
            bsum.x += v.x; bsum.y += v.y; bsum.z += v.z; bsum.w += v.w;
            asum += alphap[h * RSPLIT + q];
        }
        float4 g = ((const float4*)bgA)[tid];
        ((float4*)z)[tid] = make_float4(bsum.x + asum * g.x, bsum.y + asum * g.y,
                                        bsum.z + asum * g.z, bsum.w + asum * g.w);
    }
    __syncthreads();

    int e = blockIdx.x * 4 + wave;
    const float4* wr = (const float4*)(Wo + (size_t)e * EE);
    const float4* z4 = (const float4*)z;
    float p = 0.f;
#pragma unroll
    for (int it = 0; it < 4; ++it) {
        float4 w = wr[it * 64 + lane], zz = z4[it * 64 + lane];
        p += w.x * zz.x + w.y * zz.y + w.z * zz.z + w.w * zz.w;
    }
#pragma unroll
    for (int off = 32; off; off >>= 1) p += __shfl_xor(p, off);
    if (lane == 0) out[e] = bo[e] + p / (float)L;
}

extern "C" void kernel_launch(void* const* d_in, const int* in_sizes, int n_in,
                              void* d_out, int out_size, void* d_ws, size_t ws_size,
                              hipStream_t stream) {
    const float* x   = (const float*)d_in[0];
    const float* Wq  = (const float*)d_in[1];
    const float* bq  = (const float*)d_in[2];
    const float* Wk  = (const float*)d_in[3];
    const float* bk  = (const float*)d_in[4];
    const float* Wv  = (const float*)d_in[5];
    const float* bv  = (const float*)d_in[6];
    const float* Wo  = (const float*)d_in[7];
    const float* bo  = (const float*)d_in[8];
    const int*   seg = (const int*)d_in[9];
    const int*   pos = (const int*)d_in[10];
    float*       out = (float*)d_out;
    float*       ws  = (float*)d_ws;

    d1_kernel<<<NCOL + NPROJ, 256, 0, stream>>>(x, Wq, bq, Wk, bk, Wv, bv,
                                                seg, pos, ws);
    d2_kernel<<<NBG + HH * RSPLIT, 256, 0, stream>>>(Wv, bv, seg, pos, ws);
    d3_kernel<<<EE / 4, 256, 0, stream>>>(Wo, bo, seg, pos, ws, out);
}

// Round 10
// 116.975 us; speedup vs baseline: 1.7575x; 1.7575x over previous
//
#include <hip/hip_runtime.h>
#include <math.h>

#define SS 4096
#define EE 1024
#define HH 16
#define DD 64
#define RMAX 128     // max supported segment length (actual ~64 +/- 8)
#define NCOL 128     // colsum blocks in D1
#define NPROJ 192    // 3 m * 32 etiles * 2 rowblocks
#define NBG 64       // bgA GEMV blocks in D2
#define RSPLIT 4     // attn blocks per head

// ---------------------------------------------------------------------------
// ws layout (float offsets). LESSON (r8/r9): never read ws with 4KB-strided
// column patterns after a dispatch boundary — same-channel serialization at
// ~44 GB/s. All ws tensors below are stored so consumers read CONTIGUOUS runs.
//   sumx   [EE]              0      (atomic colsum accumulator; memset each call)
//   bgA    [EE]              1024   (V_all = S*bv + Wv.sumx)
//   betap  [64][64]          2048
//   alphap [64]              6144
//   qh     [HH][RMAX][DD]    8192     (per-head row-contiguous)
//   kTh    [HH][DD][RMAX]    8192+131072   (per-head, d-major: transposed K)
//   vh     [HH][RMAX][DD]    8192+262144
// 3 dispatches + 1 tiny memset; boundaries are the only grid-wide sync.
// ---------------------------------------------------------------------------

__device__ __forceinline__ void seg_scan(const int* __restrict__ seg,
                                         const int* __restrict__ posp,
                                         int* sh, int& s0, int& L) {
    if (threadIdx.x == 0) { sh[0] = SS; sh[1] = -1; }
    __syncthreads();
    int sid = seg[posp[0]];
    int lmin = SS, lmax = -1;
    for (int i = threadIdx.x; i < SS; i += 256)
        if (seg[i] == sid) { lmin = min(lmin, i); lmax = max(lmax, i); }
#pragma unroll
    for (int off = 32; off; off >>= 1) {
        lmin = min(lmin, __shfl_xor(lmin, off));
        lmax = max(lmax, __shfl_xor(lmax, off));
    }
    if ((threadIdx.x & 63) == 0) { atomicMin(&sh[0], lmin); atomicMax(&sh[1], lmax); }
    __syncthreads();
    s0 = sh[0];
    L  = sh[1] - sh[0] + 1;
    if (L > RMAX) L = RMAX;
    if (L < 1)    L = 1;
}

// -------- D1: colsum -> atomic sumx (128 blk) || QKV projection (192 blk) ----
__global__ __launch_bounds__(256) void d1_kernel(
    const float* __restrict__ x,
    const float* __restrict__ Wq, const float* __restrict__ bq,
    const float* __restrict__ Wk, const float* __restrict__ bk,
    const float* __restrict__ Wv, const float* __restrict__ bv,
    const int* __restrict__ seg, const int* __restrict__ posp,
    float* __restrict__ ws) {
    __shared__ float xs[128 * 65];   // [k][r]
    __shared__ float ws2[128 * 36];  // [k][e], 32 e per block
    __shared__ int   sh[2];
    float* sumx = ws;
    float* qh   = ws + 8192;
    float* kTh  = qh + (size_t)HH * RMAX * DD;
    float* vh   = kTh + (size_t)HH * DD * RMAX;

    int bid = blockIdx.x, tid = threadIdx.x;
    int lane = tid & 63, wave = tid >> 6;

    if (bid < NCOL) {
        // stream 32 full rows (contiguous), atomic-add partial into sumx
        int r0 = bid * (SS / NCOL);
        const float4* x4 = (const float4*)x;
        float4 a = make_float4(0.f, 0.f, 0.f, 0.f);
#pragma unroll 8
        for (int r = 0; r < SS / NCOL; ++r) {
            float4 v = x4[(size_t)(r0 + r) * 256 + tid];
            a.x += v.x; a.y += v.y; a.z += v.z; a.w += v.w;
        }
        atomicAdd(&sumx[4 * tid + 0], a.x);
        atomicAdd(&sumx[4 * tid + 1], a.y);
        atomicAdd(&sumx[4 * tid + 2], a.z);
        atomicAdd(&sumx[4 * tid + 3], a.w);
        return;
    }

    int pid  = bid - NCOL;           // 0..191
    int m    = pid % 3;
    int rest = pid / 3;              // 0..63
    int et   = rest & 31;            // 32-col tile
    int ry   = rest >> 5;            // row-block 0/1

    int s0, L;
    seg_scan(seg, posp, sh, s0, L);
    int Lp = (L + 63) & ~63;
    int r0 = ry * 64;
    if (r0 >= Lp) return;

    const float* W = (m == 0) ? Wq : ((m == 1) ? Wk : Wv);
    const float* b = (m == 0) ? bq : ((m == 1) ? bk : bv);

    float acc[8] = {0.f, 0.f, 0.f, 0.f, 0.f, 0.f, 0.f, 0.f};
    for (int kr = 0; kr < 8; ++kr) {
        int k0 = kr * 128;
        __syncthreads();
        for (int idx = tid; idx < 2048; idx += 256) {   // xs: 64 r x 32 k4
            int k4 = idx & 31, r = idx >> 5;
            float4 v = make_float4(0.f, 0.f, 0.f, 0.f);
            if (r0 + r < L)
                v = *(const float4*)(x + (size_t)(s0 + r0 + r) * EE + k0 + k4 * 4);
            xs[(k4 * 4 + 0) * 65 + r] = v.x;
            xs[(k4 * 4 + 1) * 65 + r] = v.y;
            xs[(k4 * 4 + 2) * 65 + r] = v.z;
            xs[(k4 * 4 + 3) * 65 + r] = v.w;
        }
        for (int idx = tid; idx < 1024; idx += 256) {   // ws2: 32 e x 32 k4
            int k4 = idx & 31, e = idx >> 5;
            float4 v = *(const float4*)(W + (size_t)(et * 32 + e) * EE + k0 + k4 * 4);
            ws2[(k4 * 4 + 0) * 36 + e] = v.x;
            ws2[(k4 * 4 + 1) * 36 + e] = v.y;
            ws2[(k4 * 4 + 2) * 36 + e] = v.z;
            ws2[(k4 * 4 + 3) * 36 + e] = v.w;
        }
        __syncthreads();
#pragma unroll 4
        for (int k = 0; k < 128; ++k) {
            float xr = xs[k * 65 + lane];
            const float4* wp = (const float4*)&ws2[k * 36 + (wave << 3)];
            float4 w0 = wp[0], w1 = wp[1];
            acc[0] += w0.x * xr; acc[1] += w0.y * xr;
            acc[2] += w0.z * xr; acc[3] += w0.w * xr;
            acc[4] += w1.x * xr; acc[5] += w1.y * xr;
            acc[6] += w1.z * xr; acc[7] += w1.w * xr;
        }
    }
    int rg = r0 + lane;               // < Lp always
    int eb = et * 32 + (wave << 3);   // 8 cols, all within one head
    int h  = eb >> 6;
    int d0 = eb & 63;
    float vals[8];
    if (rg < L) {
#pragma unroll
        for (int j = 0; j < 8; ++j) vals[j] = acc[j] + b[eb + j];
    } else {
#pragma unroll
        for (int j = 0; j < 8; ++j) vals[j] = 0.f;    // zero pad rows L..Lp-1
    }
    if (m == 1) {
        // transposed K: kTh[h][d][rg] — lanes(rg) contiguous per d
#pragma unroll
        for (int j = 0; j < 8; ++j)
            kTh[((size_t)h * DD + d0 + j) * RMAX + rg] = vals[j];
    } else {
        float* y = (m == 0) ? qh : vh;  // [h][r][d] row-contiguous
        float* dst = y + ((size_t)h * RMAX + rg) * DD + d0;
        *(float4*)dst       = make_float4(vals[0], vals[1], vals[2], vals[3]);
        *(float4*)(dst + 4) = make_float4(vals[4], vals[5], vals[6], vals[7]);
    }
}

// -------- D2: bgA GEMV (64 blk) || attention beta/alpha (64 blk) --------
__global__ __launch_bounds__(256) void d2_kernel(
    const float* __restrict__ Wv, const float* __restrict__ bv,
    const int* __restrict__ seg, const int* __restrict__ posp,
    float* __restrict__ ws) {
    __shared__ float kT[64 * 128];     // [d][t]  32 KB
    __shared__ float vS[128 * 64];     // [t][d]  32 KB
    __shared__ float sc[4 * 128];
    __shared__ float vsum[64];
    __shared__ float mwp[4][64];
    __shared__ float awp[4];
    __shared__ int   sh[2];
    const float* sumx = ws;
    float* bgA    = ws + 1024;
    float* betap  = ws + 2048;
    float* alphap = ws + 6144;
    const float* qh  = ws + 8192;
    const float* kTh = qh + (size_t)HH * RMAX * DD;
    const float* vh  = kTh + (size_t)HH * DD * RMAX;

    int bid = blockIdx.x, tid = threadIdx.x;
    int lane = tid & 63, wave = tid >> 6;

    if (bid < NBG) {
        // bgA[e] = S*bv[e] + Wv[e,:].sumx ; 16 e per block, 16 thr per e
        int e = bid * 16 + (tid >> 4);
        int j = tid & 15;
        const float4* wr  = (const float4*)(Wv + (size_t)e * EE);
        const float4* sx4 = (const float4*)sumx;
        float p = 0.f;
#pragma unroll
        for (int jj = 0; jj < 16; ++jj) {
            float4 w = wr[jj * 16 + j], z = sx4[jj * 16 + j];
            p += w.x * z.x + w.y * z.y + w.z * z.z + w.w * z.w;
        }
        p += __shfl_xor(p, 8);
        p += __shfl_xor(p, 4);
        p += __shfl_xor(p, 2);
        p += __shfl_xor(p, 1);
        if (j == 0) bgA[e] = p + (float)SS * bv[e];
        return;
    }

    int aid = bid - NBG;              // 0..63
    int h   = aid / RSPLIT;
    int q4  = aid % RSPLIT;

    int s0, L;
    seg_scan(seg, posp, sh, s0, L);
    int Lp = (L + 63) & ~63;
    int nt = Lp >> 6;

    // stage K^T and V slabs: LINEAR contiguous 32 KB copies (channel-friendly)
    {
        const float4* src = (const float4*)(kTh + (size_t)h * DD * RMAX);
        float4* dst = (float4*)kT;
        for (int i = tid; i < 64 * 128 / 4; i += 256) dst[i] = src[i];
        const float4* src2 = (const float4*)(vh + (size_t)h * RMAX * DD);
        float4* dst2 = (float4*)vS;
        for (int i = tid; i < 128 * 64 / 4; i += 256) dst2[i] = src2[i];
    }
    __syncthreads();

    // vsum[d] = sum_t vS[t][d]  (pad rows are zero)
    {
        int d = tid >> 2, q = tid & 3;
        float s = 0.f;
        for (int t = q; t < Lp; t += 4) s += vS[t * 64 + d];
        s += __shfl_xor(s, 1);
        s += __shfl_xor(s, 2);
        if (q == 0) vsum[d] = s;
    }
    __syncthreads();

    float bw = 0.f;   // per-lane (d) sum of acc/Z
    float aw = 0.f;   // wave-uniform sum of exp(-m)/Z
    int rpb = Lp / RSPLIT;
    int rlo = q4 * rpb;
    int rhi = rlo + rpb; if (rhi > L) rhi = L;
    float* scw = sc + wave * 128;
    for (int r = rlo + wave; r < rhi; r += 4) {
        float qreg = qh[((size_t)h * RMAX + r) * DD + lane];
        float mmax = 0.f;   // zero background participates in row max
        for (int c = 0; c < nt; ++c) {
            float s = 0.f;
            const float* kp = kT + c * 64 + lane;
#pragma unroll
            for (int d = 0; d < 64; ++d) s += __shfl(qreg, d) * kp[d * 128];
            scw[c * 64 + lane] = s;
            mmax = fmaxf(mmax, (c * 64 + lane) < L ? s : -3.0e38f);
        }
#pragma unroll
        for (int off = 32; off; off >>= 1) mmax = fmaxf(mmax, __shfl_xor(mmax, off));
        float Zl = 0.f;
        for (int c = 0; c < nt; ++c) {
            float w = ((c * 64 + lane) < L) ? __expf(scw[c * 64 + lane] - mmax) : 0.f;
            Zl += w;
            scw[c * 64 + lane] = w;
        }
#pragma unroll
        for (int off = 32; off; off >>= 1) Zl += __shfl_xor(Zl, off);
        float em = __expf(-mmax);
        float Z  = Zl + (float)(SS - L) * em;
        float acc = 0.f;
        for (int c = 0; c < nt; ++c) {
            const float* vp  = vS + c * 64 * 64 + lane;
            const float* scc = scw + c * 64;
#pragma unroll 16
            for (int tt = 0; tt < 64; ++tt) acc += scc[tt] * vp[tt * 64];
        }
        float invZ = 1.0f / Z;
        bw += acc * invZ;
        aw += em * invZ;
    }
    mwp[wave][lane] = bw;
    if (lane == 0) awp[wave] = aw;
    __syncthreads();
    if (tid < 64) {
        float asum = awp[0] + awp[1] + awp[2] + awp[3];
        float beta = mwp[0][tid] + mwp[1][tid] + mwp[2][tid] + mwp[3][tid]
                   - asum * vsum[tid];
        betap[aid * 64 + tid] = beta;
        if (tid == 0) alphap[aid] = asum;
    }
}

// -------- D3: out[e] = bo[e] + Wo[e,:].(beta~ + alpha o bgA) / L --------
__global__ __launch_bounds__(256) void d3_kernel(
    const float* __restrict__ Wo, const float* __restrict__ bo,
    const int* __restrict__ seg, const int* __restrict__ posp,
    const float* __restrict__ ws, float* __restrict__ out) {
    __shared__ float z[EE];
    __shared__ int   sh[2];
    const float* bgA    = ws + 1024;
    const float* betap  = ws + 2048;
    const float* alphap = ws + 6144;

    int tid = threadIdx.x;
    int lane = tid & 63, wave = tid >> 6;
    int s0, L;
    seg_scan(seg, posp, sh, s0, L);

    {   // z[j] = sum_q betap[h*4+q][d] + (sum_q alphap[h*4+q]) * bgA[j]
        int h = tid >> 4;                 // float4 index -> head
        const float4* bp4 = (const float4*)betap;
        float4 bsum = make_float4(0.f, 0.f, 0.f, 0.f);
        float  asum = 0.f;
#pragma unroll
        for (int q = 0; q < RSPLIT; ++q) {
            float4 v = bp4[(h * RSPLIT + q) * 16 + (tid & 15)];
            bsum.x += v.x; bsum.y += v.y; bsum.z += v.z; bsum.w += v.w;
            asum += alphap[h * RSPLIT + q];
        }
        float4 g = ((const float4*)bgA)[tid];
        ((float4*)z)[tid] = make_float4(bsum.x + asum * g.x, bsum.y + asum * g.y,
                                        bsum.z + asum * g.z, bsum.w + asum * g.w);
    }
    __syncthreads();

    int e = blockIdx.x * 4 + wave;
    const float4* wr = (const float4*)(Wo + (size_t)e * EE);
    const float4* z4 = (const float4*)z;
    float p = 0.f;
#pragma unroll
    for (int it = 0; it < 4; ++it) {
        float4 w = wr[it * 64 + lane], zz = z4[it * 64 + lane];
        p += w.x * zz.x + w.y * zz.y + w.z * zz.z + w.w * zz.w;
    }
#pragma unroll
    for (int off = 32; off; off >>= 1) p += __shfl_xor(p, off);
    if (lane == 0) out[e] = bo[e] + p / (float)L;
}

extern "C" void kernel_launch(void* const* d_in, const int* in_sizes, int n_in,
                              void* d_out, int out_size, void* d_ws, size_t ws_size,
                              hipStream_t stream) {
    const float* x   = (const float*)d_in[0];
    const float* Wq  = (const float*)d_in[1];
    const float* bq  = (const float*)d_in[2];
    const float* Wk  = (const float*)d_in[3];
    const float* bk  = (const float*)d_in[4];
    const float* Wv  = (const float*)d_in[5];
    const float* bv  = (const float*)d_in[6];
    const float* Wo  = (const float*)d_in[7];
    const float* bo  = (const float*)d_in[8];
    const int*   seg = (const int*)d_in[9];
    const int*   pos = (const int*)d_in[10];
    float*       out = (float*)d_out;
    float*       ws  = (float*)d_ws;

    hipMemsetAsync(ws, 0, EE * sizeof(float), stream);   // zero sumx accumulator
    d1_kernel<<<NCOL + NPROJ, 256, 0, stream>>>(x, Wq, bq, Wk, bk, Wv, bv,
                                                seg, pos, ws);
    d2_kernel<<<NBG + HH * RSPLIT, 256, 0, stream>>>(Wv, bv, seg, pos, ws);
    d3_kernel<<<EE / 4, 256, 0, stream>>>(Wo, bo, seg, pos, ws, out);
}

// Round 11
// 86.193 us; speedup vs baseline: 2.3852x; 1.3571x over previous
//
#include <hip/hip_runtime.h>
#include <math.h>

#define SS 4096
#define EE 1024
#define HH 16
#define DD 64
#define RMAX 128     // max supported segment length (actual ~64 +/- 8)
#define NCOL 128     // colsum blocks in D0
#define NTR  8       // x-transpose blocks in D0
#define NRED 8       // sumx reduce blocks in D1
#define NPROJ 768    // 3 m * 128 e-blocks(8e) * 2 r-tiles
#define NBG 64       // bgA GEMV blocks in D2
#define RSPLIT 4     // attn blocks per head

// ---------------------------------------------------------------------------
// ws float offsets. LESSONS: (r9/r10) no 4KB-strided reads anywhere — every
// consumer reads contiguous runs; (r3) no bulk global atomics; (r5/r7) no
// software grid barriers — dispatch boundaries only.
//   meta   int[0..1]        (s0, L) written by D0
//   sumx   [EE]        @64
//   bgA    [EE]        @1088
//   betap  [64][64]    @2112
//   alphap [64]        @6208
//   partT  [EE][NCOL]  @8192    colsum partials, TRANSPOSED (e-major)
//   xT     [EE][RMAX]  @139264  x segment transposed, 512B contiguous rows
//   qh     [HH][RMAX][DD] @270336
//   kTh    [HH][DD][RMAX] @401408
//   vh     [HH][RMAX][DD] @532480
// ---------------------------------------------------------------------------
#define OFF_SUMX  64
#define OFF_BGA   1088
#define OFF_BETA  2112
#define OFF_ALPHA 6208
#define OFF_PART  8192
#define OFF_XT    (OFF_PART + EE * NCOL)
#define OFF_QH    (OFF_XT + EE * RMAX)
#define OFF_KTH   (OFF_QH + HH * RMAX * DD)
#define OFF_VH    (OFF_KTH + HH * DD * RMAX)

__device__ __forceinline__ void seg_scan(const int* __restrict__ seg,
                                         const int* __restrict__ posp,
                                         int* sh, int& s0, int& L) {
    if (threadIdx.x == 0) { sh[0] = SS; sh[1] = -1; }
    __syncthreads();
    int sid = seg[posp[0]];
    int lmin = SS, lmax = -1;
    for (int i = threadIdx.x; i < SS; i += 256)
        if (seg[i] == sid) { lmin = min(lmin, i); lmax = max(lmax, i); }
#pragma unroll
    for (int off = 32; off; off >>= 1) {
        lmin = min(lmin, __shfl_xor(lmin, off));
        lmax = max(lmax, __shfl_xor(lmax, off));
    }
    if ((threadIdx.x & 63) == 0) { atomicMin(&sh[0], lmin); atomicMax(&sh[1], lmax); }
    __syncthreads();
    s0 = sh[0];
    L  = sh[1] - sh[0] + 1;
    if (L > RMAX) L = RMAX;
    if (L < 1)    L = 1;
}

// -------- D0: colsum -> partT (128 blk) || x-seg transpose -> xT (8 blk) ----
__global__ __launch_bounds__(256) void d0_kernel(
    const float* __restrict__ x, const int* __restrict__ seg,
    const int* __restrict__ posp, float* __restrict__ ws) {
    int bid = blockIdx.x, tid = threadIdx.x;
    if (bid < NCOL) {
        float* partT = ws + OFF_PART;
        int r0 = bid * (SS / NCOL);
        const float4* x4 = (const float4*)x;
        float4 a = make_float4(0.f, 0.f, 0.f, 0.f);
#pragma unroll 8
        for (int r = 0; r < SS / NCOL; ++r) {
            float4 v = x4[(size_t)(r0 + r) * 256 + tid];
            a.x += v.x; a.y += v.y; a.z += v.z; a.w += v.w;
        }
        partT[(size_t)(4 * tid + 0) * NCOL + bid] = a.x;
        partT[(size_t)(4 * tid + 1) * NCOL + bid] = a.y;
        partT[(size_t)(4 * tid + 2) * NCOL + bid] = a.z;
        partT[(size_t)(4 * tid + 3) * NCOL + bid] = a.w;
        return;
    }
    __shared__ float t[128 * 129];
    __shared__ int sh[2];
    int s0, L;
    seg_scan(seg, posp, sh, s0, L);
    int kb = bid - NCOL;
    if (kb == 0 && tid == 0) { ((int*)ws)[0] = s0; ((int*)ws)[1] = L; }
    int k0 = kb * 128;
    for (int idx = tid; idx < 128 * 32; idx += 256) {
        int r = idx >> 5, c4 = idx & 31;
        float4 v = make_float4(0.f, 0.f, 0.f, 0.f);
        if (r < L) v = *(const float4*)(x + (size_t)(s0 + r) * EE + k0 + c4 * 4);
        t[r * 129 + c4 * 4 + 0] = v.x;
        t[r * 129 + c4 * 4 + 1] = v.y;
        t[r * 129 + c4 * 4 + 2] = v.z;
        t[r * 129 + c4 * 4 + 3] = v.w;
    }
    __syncthreads();
    float* xT = ws + OFF_XT;
    for (int idx = tid; idx < 128 * 32; idx += 256) {
        int k = idx >> 5, r4 = idx & 31;
        float4 o;
        o.x = t[(r4 * 4 + 0) * 129 + k];
        o.y = t[(r4 * 4 + 1) * 129 + k];
        o.z = t[(r4 * 4 + 2) * 129 + k];
        o.w = t[(r4 * 4 + 3) * 129 + k];
        *(float4*)(xT + (size_t)(k0 + k) * RMAX + r4 * 4) = o;
    }
}

// -------- D1: sumx reduce (8 blk) || QKV projection (768 blk) --------
// proj: 8 W-rows per block, lane = r, 4 waves split K. x via coalesced L2
// column loads of xT; W via wave-uniform (scalar-path) loads. No staging.
__global__ __launch_bounds__(256) void d1_kernel(
    const float* __restrict__ Wq, const float* __restrict__ bq,
    const float* __restrict__ Wk, const float* __restrict__ bk,
    const float* __restrict__ Wv, const float* __restrict__ bv,
    float* __restrict__ ws) {
    int bid = blockIdx.x, tid = threadIdx.x;
    if (bid < NRED) {
        const float* partT = ws + OFF_PART;
        int e  = bid * 128 + (tid >> 1);
        int c0 = (tid & 1) * 64;
        const float4* p4 = (const float4*)(partT + (size_t)e * NCOL + c0);
        float4 s4 = make_float4(0.f, 0.f, 0.f, 0.f);
#pragma unroll
        for (int i = 0; i < 16; ++i) {
            float4 v = p4[i];
            s4.x += v.x; s4.y += v.y; s4.z += v.z; s4.w += v.w;
        }
        float s = s4.x + s4.y + s4.z + s4.w;
        s += __shfl_xor(s, 1);
        if ((tid & 1) == 0) (ws + OFF_SUMX)[e] = s;
        return;
    }
    __shared__ float red[4 * 8 * 66];
    int L  = ((const int*)ws)[1];
    int Lp = (L + 63) & ~63;
    int pid = bid - NRED;
    int m   = pid >> 8;           // 0..2
    int rem = pid & 255;
    int eb  = rem >> 1;           // 0..127
    int rt  = rem & 1;
    int r0  = rt * 64;
    if (r0 >= Lp) return;
    int e0 = eb * 8;
    const float* W = (m == 0) ? Wq : ((m == 1) ? Wk : Wv);
    const float* b = (m == 0) ? bq : ((m == 1) ? bk : bv);
    int lane = tid & 63;
    int w4 = __builtin_amdgcn_readfirstlane(tid >> 6);   // wave id, uniform
    const float* xcol = ws + OFF_XT + r0 + lane;
    int kbase = w4 * 256;
    const float* wr0 = W + (size_t)e0 * EE + kbase;      // uniform
    float acc[8] = {0.f, 0.f, 0.f, 0.f, 0.f, 0.f, 0.f, 0.f};
    for (int kk = 0; kk < 256; kk += 8) {
        float xv[8];
#pragma unroll
        for (int u = 0; u < 8; ++u)
            xv[u] = xcol[(size_t)(kbase + kk + u) * RMAX];
#pragma unroll
        for (int j = 0; j < 8; ++j) {
            const float* wj = wr0 + (size_t)j * EE + kk;
#pragma unroll
            for (int u = 0; u < 8; ++u) acc[j] += xv[u] * wj[u];
        }
    }
#pragma unroll
    for (int j = 0; j < 8; ++j) red[(w4 * 8 + j) * 66 + lane] = acc[j];
    __syncthreads();
    int jj = tid >> 6;
    int rg = r0 + lane;
    float* qh  = ws + OFF_QH;
    float* kTh = ws + OFF_KTH;
    float* vh  = ws + OFF_VH;
    int h = e0 >> 6, d0 = e0 & 63;
#pragma unroll
    for (int p = jj; p < 8; p += 4) {
        float v = 0.f;
        if (rg < L)
            v = red[(0 * 8 + p) * 66 + lane] + red[(1 * 8 + p) * 66 + lane]
              + red[(2 * 8 + p) * 66 + lane] + red[(3 * 8 + p) * 66 + lane]
              + b[e0 + p];
        if (m == 1) kTh[(size_t)(h * DD + d0 + p) * RMAX + rg] = v;
        else        ((m == 0) ? qh : vh)[((size_t)h * RMAX + rg) * DD + d0 + p] = v;
    }
}

// -------- D2: bgA GEMV (64 blk) || attention beta/alpha (64 blk) --------
__global__ __launch_bounds__(256) void d2_kernel(
    const float* __restrict__ Wv, const float* __restrict__ bv,
    float* __restrict__ ws) {
    __shared__ float kT[64 * 128];     // [d][t]
    __shared__ float vS[128 * 64];     // [t][d]
    __shared__ float sc[4 * 128];
    __shared__ float vsum[64];
    __shared__ float mwp[4][64];
    __shared__ float awp[4];
    const float* sumx = ws + OFF_SUMX;
    float* bgA    = ws + OFF_BGA;
    float* betap  = ws + OFF_BETA;
    float* alphap = ws + OFF_ALPHA;
    const float* qh  = ws + OFF_QH;
    const float* kTh = ws + OFF_KTH;
    const float* vh  = ws + OFF_VH;

    int bid = blockIdx.x, tid = threadIdx.x;
    int lane = tid & 63, wave = tid >> 6;
    int L  = ((const int*)ws)[1];
    int Lp = (L + 63) & ~63;
    int nt = Lp >> 6;

    if (bid < NBG) {
        int e = bid * 16 + (tid >> 4);
        int j = tid & 15;
        const float4* wr  = (const float4*)(Wv + (size_t)e * EE);
        const float4* sx4 = (const float4*)sumx;
        float p = 0.f;
#pragma unroll
        for (int jj = 0; jj < 16; ++jj) {
            float4 w = wr[jj * 16 + j], z = sx4[jj * 16 + j];
            p += w.x * z.x + w.y * z.y + w.z * z.z + w.w * z.w;
        }
        p += __shfl_xor(p, 8);
        p += __shfl_xor(p, 4);
        p += __shfl_xor(p, 2);
        p += __shfl_xor(p, 1);
        if (j == 0) bgA[e] = p + (float)SS * bv[e];
        return;
    }

    int aid = bid - NBG;              // 0..63
    int h   = aid / RSPLIT;
    int q4  = aid % RSPLIT;

    {   // stage: linear contiguous 32 KB copies
        const float4* src = (const float4*)(kTh + (size_t)h * DD * RMAX);
        float4* dst = (float4*)kT;
        for (int i = tid; i < 64 * 128 / 4; i += 256) dst[i] = src[i];
        const float4* src2 = (const float4*)(vh + (size_t)h * RMAX * DD);
        float4* dst2 = (float4*)vS;
        for (int i = tid; i < 128 * 64 / 4; i += 256) dst2[i] = src2[i];
    }
    __syncthreads();

    {   // vsum[d] = sum_t vS[t][d]  (pad rows are zero)
        int d = tid >> 2, q = tid & 3;
        float s = 0.f;
        for (int t = q; t < Lp; t += 4) s += vS[t * 64 + d];
        s += __shfl_xor(s, 1);
        s += __shfl_xor(s, 2);
        if (q == 0) vsum[d] = s;
    }
    __syncthreads();

    float bw = 0.f, aw = 0.f;
    int rpb = Lp / RSPLIT;
    int rlo = q4 * rpb;
    int rhi = rlo + rpb; if (rhi > L) rhi = L;
    float* scw = sc + wave * 128;
    for (int r = rlo + wave; r < rhi; r += 4) {
        float qreg = qh[((size_t)h * RMAX + r) * DD + lane];
        float mmax = 0.f;   // zero background participates in row max
        for (int c = 0; c < nt; ++c) {
            float s = 0.f;
            const float* kp = kT + c * 64 + lane;
#pragma unroll
            for (int d = 0; d < 64; ++d) s += __shfl(qreg, d) * kp[d * 128];
            scw[c * 64 + lane] = s;
            mmax = fmaxf(mmax, (c * 64 + lane) < L ? s : -3.0e38f);
        }
#pragma unroll
        for (int off = 32; off; off >>= 1) mmax = fmaxf(mmax, __shfl_xor(mmax, off));
        float Zl = 0.f;
        for (int c = 0; c < nt; ++c) {
            float w = ((c * 64 + lane) < L) ? __expf(scw[c * 64 + lane] - mmax) : 0.f;
            Zl += w;
            scw[c * 64 + lane] = w;
        }
#pragma unroll
        for (int off = 32; off; off >>= 1) Zl += __shfl_xor(Zl, off);
        float em = __expf(-mmax);
        float Z  = Zl + (float)(SS - L) * em;
        float acc = 0.f;
        for (int c = 0; c < nt; ++c) {
            const float* vp  = vS + c * 64 * 64 + lane;
            const float* scc = scw + c * 64;
#pragma unroll 16
            for (int tt = 0; tt < 64; ++tt) acc += scc[tt] * vp[tt * 64];
        }
        float invZ = 1.0f / Z;
        bw += acc * invZ;
        aw += em * invZ;
    }
    mwp[wave][lane] = bw;
    if (lane == 0) awp[wave] = aw;
    __syncthreads();
    if (tid < 64) {
        float asum = awp[0] + awp[1] + awp[2] + awp[3];
        float beta = mwp[0][tid] + mwp[1][tid] + mwp[2][tid] + mwp[3][tid]
                   - asum * vsum[tid];
        betap[aid * 64 + tid] = beta;
        if (tid == 0) alphap[aid] = asum;
    }
}

// -------- D3: out[e] = bo[e] + Wo[e,:].(beta~ + alpha o bgA) / L --------
__global__ __launch_bounds__(256) void d3_kernel(
    const float* __restrict__ Wo, const float* __restrict__ bo,
    const float* __restrict__ ws, float* __restrict__ out) {
    __shared__ float z[EE];
    const float* bgA    = ws + OFF_BGA;
    const float* betap  = ws + OFF_BETA;
    const float* alphap = ws + OFF_ALPHA;
    int tid = threadIdx.x;
    int lane = tid & 63, wave = tid >> 6;
    int L = ((const int*)ws)[1];

    {   // z = per-head beta sums + (per-head alpha sums) * bgA
        int h = tid >> 4;                 // float4 index -> head
        const float4* bp4 = (const float4*)betap;
        float4 bsum = make_float4(0.f, 0.f, 0.f, 0.f);
        float  asum = 0.f;
#pragma unroll
        for (int q = 0; q < RSPLIT; ++q) {
            float4 v = bp4[(h * RSPLIT + q) * 16 + (tid & 15)];
            bsum.x += v.x; bsum.y += v.y; bsum.z += v.z; bsum.w += v.w;
            asum += alphap[h * RSPLIT + q];
        }
        float4 g = ((const float4*)bgA)[tid];
        ((float4*)z)[tid] = make_float4(bsum.x + asum * g.x, bsum.y + asum * g.y,
                                        bsum.z + asum * g.z, bsum.w + asum * g.w);
    }
    __syncthreads();

    int e = blockIdx.x * 4 + wave;
    const float4* wr = (const float4*)(Wo + (size_t)e * EE);
    const float4* z4 = (const float4*)z;
    float p = 0.f;
#pragma unroll
    for (int it = 0; it < 4; ++it) {
        float4 w = wr[it * 64 + lane], zz = z4[it * 64 + lane];
        p += w.x * zz.x + w.y * zz.y + w.z * zz.z + w.w * zz.w;
    }
#pragma unroll
    for (int off = 32; off; off >>= 1) p += __shfl_xor(p, off);
    if (lane == 0) out[e] = bo[e] + p / (float)L;
}

extern "C" void kernel_launch(void* const* d_in, const int* in_sizes, int n_in,
                              void* d_out, int out_size, void* d_ws, size_t ws_size,
                              hipStream_t stream) {
    const float* x   = (const float*)d_in[0];
    const float* Wq  = (const float*)d_in[1];
    const float* bq  = (const float*)d_in[2];
    const float* Wk  = (const float*)d_in[3];
    const float* bk  = (const float*)d_in[4];
    const float* Wv  = (const float*)d_in[5];
    const float* bv  = (const float*)d_in[6];
    const float* Wo  = (const float*)d_in[7];
    const float* bo  = (const float*)d_in[8];
    const int*   seg = (const int*)d_in[9];
    const int*   pos = (const int*)d_in[10];
    float*       out = (float*)d_out;
    float*       ws  = (float*)d_ws;

    d0_kernel<<<NCOL + NTR, 256, 0, stream>>>(x, seg, pos, ws);
    d1_kernel<<<NRED + NPROJ, 256, 0, stream>>>(Wq, bq, Wk, bk, Wv, bv, ws);
    d2_kernel<<<NBG + HH * RSPLIT, 256, 0, stream>>>(Wv, bv, ws);
    d3_kernel<<<EE / 4, 256, 0, stream>>>(Wo, bo, ws, out);
}